// Round 9
// baseline (33.727 us; speedup 1.0000x reference)
//
#include <hip/hip_runtime.h>

// out[b,c,y,x] = sum_{i,j} Dot[b,3i+j,y,x] * V[b,c,y+i-1,x+j-1]  (zero-padded)
// b=16, c=64, h=w=128, fp32. HBM steady-state ~103 MB; floor ~16-20 us.
// Round-8 lesson: all LDS+barrier variants pin at 28-30us (26% occ, 15% VALU,
// 3.7 TB/s) while fillBuffer hits 6.8 TB/s -> block prologue (stage->barrier)
// serialization suspected. This round: NO LDS, NO barrier, 4-row y-strip,
// weights straight from L1 (broadcast across channel lanes), waves independent.

#define HH 128
#define WW 128
#define CC 64
#define KK 9

typedef float f4 __attribute__((ext_vector_type(4)));

__device__ __forceinline__ void accum3(f4& o, float vl, const f4& vm, float vr,
                                       const f4& d0, const f4& d1, const f4& d2)
{
    o.x += d0.x * vl   + d1.x * vm.x + d2.x * vm.y;
    o.y += d0.y * vm.x + d1.y * vm.y + d2.y * vm.z;
    o.z += d0.z * vm.y + d1.z * vm.z + d2.z * vm.w;
    o.w += d0.w * vm.z + d1.w * vm.w + d2.w * vr;
}

__global__ __launch_bounds__(256) void msa_conv2d_kernel(
    const float* __restrict__ Dot,
    const float* __restrict__ V,
    float* __restrict__ out)
{
    // 4096 blocks; XCD = n%8 (round-robin). XCD k owns contiguous chunk
    // [k*512,(k+1)*512) of L = ((b*32 + ys)*8 + cg):
    //  - all 8 channel-groups of a (b,ys) on one XCD -> weight L2/L1 reuse
    //  - adjacent ys on one XCD                      -> V halo L2 reuse
    const int n  = blockIdx.x;
    const int L  = (n & 7) * 512 + (n >> 3);
    const int b  = L >> 8;               // 0..15
    const int r2 = L & 255;
    const int ys = r2 >> 3;              // 0..31
    const int cg = r2 & 7;               // 0..7
    const int y0 = ys * 4;

    const int tid = threadIdx.x;
    const int xq  = tid & 31;            // x-quad 0..31
    const int tc  = tid >> 5;            // 0..7
    const int c   = cg * 8 + tc;
    const int x0  = xq * 4;

    const float* vC = V   + (((size_t)b * CC + c) * HH) * WW + x0;
    const float* dC = Dot + ((size_t)b * KK) * (HH * WW) + x0;
    float*       oC = out + (((size_t)b * CC + c) * HH) * WW + x0;

    const f4 z4 = {0.f, 0.f, 0.f, 0.f};

    // ---- V rows y0-1 .. y0+4: 6 independent loads, issued first. ----
    f4 r[6];
    r[0] = (y0 > 0)      ? *reinterpret_cast<const f4*>(vC + (size_t)(y0 - 1) * WW) : z4;
    #pragma unroll
    for (int i = 0; i < 4; ++i)
        r[i + 1] =         *reinterpret_cast<const f4*>(vC + (size_t)(y0 + i) * WW);
    r[5] = (y0 + 4 < HH) ? *reinterpret_cast<const f4*>(vC + (size_t)(y0 + 4) * WW) : z4;

    // Halos via cross-lane shuffle (width 32 = one channel's x-row).
    float lo[6], hi[6];
    #pragma unroll
    for (int i = 0; i < 6; ++i) {
        lo[i] = __shfl_up(r[i].w, 1, 32);
        hi[i] = __shfl_down(r[i].x, 1, 32);
    }
    if (xq == 0) {
        #pragma unroll
        for (int i = 0; i < 6; ++i) lo[i] = 0.f;
    }
    if (xq == 31) {
        #pragma unroll
        for (int i = 0; i < 6; ++i) hi[i] = 0.f;
    }

    // ---- Per output row: 9 weight f4 from cache (L1 broadcast), 3x accum3. --
    #pragma unroll
    for (int y = 0; y < 4; ++y) {
        const float* dRow = dC + (size_t)(y0 + y) * WW;
        f4 w[KK];
        #pragma unroll
        for (int k = 0; k < KK; ++k)
            w[k] = *reinterpret_cast<const f4*>(dRow + (size_t)k * (HH * WW));

        f4 o = z4;
        accum3(o, lo[y    ], r[y    ], hi[y    ], w[0], w[1], w[2]);
        accum3(o, lo[y + 1], r[y + 1], hi[y + 1], w[3], w[4], w[5]);
        accum3(o, lo[y + 2], r[y + 2], hi[y + 2], w[6], w[7], w[8]);

        *reinterpret_cast<f4*>(oC + (size_t)(y0 + y) * WW) = o;
    }
}

extern "C" void kernel_launch(void* const* d_in, const int* in_sizes, int n_in,
                              void* d_out, int out_size, void* d_ws, size_t ws_size,
                              hipStream_t stream)
{
    const float* Dot = (const float*)d_in[0];  // (16, 9, 128, 128)
    const float* V   = (const float*)d_in[1];  // (16, 64, 128, 128)
    float* out       = (float*)d_out;          // (16, 64, 128, 128)

    msa_conv2d_kernel<<<dim3(4096), 256, 0, stream>>>(Dot, V, out);
}

// Round 10
// 28.401 us; speedup vs baseline: 1.1875x; 1.1875x over previous
//
#include <hip/hip_runtime.h>

// out[b,c,y,x] = sum_{i,j} Dot[b,3i+j,y,x] * V[b,c,y+i-1,x+j-1]  (zero-padded)
// b=16, c=64, h=w=128, fp32. HBM steady-state ~103 MB; floor ~17 us.
// Round-9 lesson: weights-from-global = 2.9 VMEM/output (vs 0.89) -> L1/issue
// bound, 33.7us. Keep LDS weight sharing. This round: collapse the block's TWO
// serial memory round-trips (stage->wait->barrier->Vload->wait) into ONE:
// V loads issued first, Dot staged via global_load_lds (async, no VGPR trip),
// single vmcnt drain at the barrier completes both streams together.

#define HH 128
#define WW 128
#define CC 64
#define KK 9

typedef float f4 __attribute__((ext_vector_type(4)));

__device__ __forceinline__ void accum3(f4& o, float vl, const f4& vm, float vr,
                                       const f4& d0, const f4& d1, const f4& d2)
{
    o.x += d0.x * vl   + d1.x * vm.x + d2.x * vm.y;
    o.y += d0.y * vm.x + d1.y * vm.y + d2.y * vm.z;
    o.z += d0.z * vm.y + d1.z * vm.z + d2.z * vm.w;
    o.w += d0.w * vm.z + d1.w * vm.w + d2.w * vr;
}

__global__ __launch_bounds__(256) void msa_conv2d_kernel(
    const float* __restrict__ Dot,
    const float* __restrict__ V,
    float* __restrict__ out)
{
    __shared__ float dotRow[2][KK][WW];   // 9216 B = 576 x 16B chunks

    // 2048 blocks; XCD = n%8 (round-robin). XCD k owns contiguous chunk
    // [k*256, (k+1)*256) of work ids L = ((b*64 + yp)*2 + ch).
    const int n   = blockIdx.x;
    const int L   = (n & 7) * 256 + (n >> 3);
    const int b   = L >> 7;             // 0..15
    const int rem = L & 127;
    const int yp  = rem >> 1;           // 0..63
    const int ch  = rem & 1;            // channel half, 0..1
    const int y0  = yp * 2;

    const int tid = threadIdx.x;
    const int tx  = tid & 31;           // x-quad 0..31
    const int tc  = tid >> 5;           // channel sub-index 0..7
    const int x0  = tx * 4;

    const bool topOK = (y0 > 0);
    const bool botOK = (y0 + 2 < HH);
    const f4 z4 = {0.f, 0.f, 0.f, 0.f};

    const float* vB = V   + ((size_t)b * CC) * (HH * WW);
    float*       oB = out + ((size_t)b * CC) * (HH * WW);

    // ---- Phase 1a: issue all 16 V loads (fly during Dot staging + barrier).
    f4 r[4][4];
    #pragma unroll
    for (int cc = 0; cc < 4; ++cc) {
        const int c = ch * 32 + cc * 8 + tc;
        const float* vC = vB + (size_t)c * (HH * WW) + x0;
        r[cc][0] = topOK ? *reinterpret_cast<const f4*>(vC + (size_t)(y0 - 1) * WW) : z4;
        r[cc][1] =         *reinterpret_cast<const f4*>(vC + (size_t)(y0    ) * WW);
        r[cc][2] =         *reinterpret_cast<const f4*>(vC + (size_t)(y0 + 1) * WW);
        r[cc][3] = botOK ? *reinterpret_cast<const f4*>(vC + (size_t)(y0 + 2) * WW) : z4;
    }

    // ---- Phase 1b: async-stage Dot[b, 0..8, y0..y0+1, :] straight to LDS.
    // Chunk t in [0,576): flat float idx = 4t = ((yy*9 + k)*128 + x4*4).
    // LDS dest is linear in t -> wave-uniform base + lane*16 (requirement met;
    // chunks 512..575 are exactly wave 0's 64 lanes).
    {
        float* ldsBase = &dotRow[0][0][0];
        #pragma unroll
        for (int rnd = 0; rnd < 2; ++rnd) {
            const int t  = tid + rnd * 256;
            const int yy = t / 288;
            const int rm = t - yy * 288;
            const int k  = rm >> 5;
            const int x4 = rm & 31;
            const float* src = Dot + (((size_t)b * KK + k) * HH + (y0 + yy)) * WW + x4 * 4;
            __builtin_amdgcn_global_load_lds(
                (const __attribute__((address_space(1))) void*)src,
                (__attribute__((address_space(3))) void*)(ldsBase + (size_t)t * 4),
                16, 0, 0);
        }
        if (tid < 64) {
            const int t  = tid + 512;
            const int yy = t / 288;
            const int rm = t - yy * 288;
            const int k  = rm >> 5;
            const int x4 = rm & 31;
            const float* src = Dot + (((size_t)b * KK + k) * HH + (y0 + yy)) * WW + x4 * 4;
            __builtin_amdgcn_global_load_lds(
                (const __attribute__((address_space(1))) void*)src,
                (__attribute__((address_space(3))) void*)(ldsBase + (size_t)t * 4),
                16, 0, 0);
        }
    }
    __syncthreads();   // one vmcnt drain completes BOTH V loads and staging

    // ---- Phase 2: weights from LDS (broadcast), compute, store.
    f4 dA[KK], dB[KK];
    #pragma unroll
    for (int k = 0; k < KK; ++k) {
        dA[k] = *reinterpret_cast<const f4*>(&dotRow[0][k][x0]);
        dB[k] = *reinterpret_cast<const f4*>(&dotRow[1][k][x0]);
    }

    #pragma unroll
    for (int cc = 0; cc < 4; ++cc) {
        const int c = ch * 32 + cc * 8 + tc;

        float l0 = __shfl_up(r[cc][0].w, 1, 32), h0 = __shfl_down(r[cc][0].x, 1, 32);
        float l1 = __shfl_up(r[cc][1].w, 1, 32), h1 = __shfl_down(r[cc][1].x, 1, 32);
        float l2 = __shfl_up(r[cc][2].w, 1, 32), h2 = __shfl_down(r[cc][2].x, 1, 32);
        float l3 = __shfl_up(r[cc][3].w, 1, 32), h3 = __shfl_down(r[cc][3].x, 1, 32);
        if (tx == 0)  { l0 = l1 = l2 = l3 = 0.f; }
        if (tx == 31) { h0 = h1 = h2 = h3 = 0.f; }

        f4 o0 = z4, o1 = z4;
        accum3(o0, l0, r[cc][0], h0, dA[0], dA[1], dA[2]);
        accum3(o0, l1, r[cc][1], h1, dA[3], dA[4], dA[5]);
        accum3(o0, l2, r[cc][2], h2, dA[6], dA[7], dA[8]);
        accum3(o1, l1, r[cc][1], h1, dB[0], dB[1], dB[2]);
        accum3(o1, l2, r[cc][2], h2, dB[3], dB[4], dB[5]);
        accum3(o1, l3, r[cc][3], h3, dB[6], dB[7], dB[8]);

        float* oC = oB + (size_t)c * (HH * WW) + x0;
        *reinterpret_cast<f4*>(oC + (size_t)(y0    ) * WW) = o0;
        *reinterpret_cast<f4*>(oC + (size_t)(y0 + 1) * WW) = o1;
    }
}

extern "C" void kernel_launch(void* const* d_in, const int* in_sizes, int n_in,
                              void* d_out, int out_size, void* d_ws, size_t ws_size,
                              hipStream_t stream)
{
    const float* Dot = (const float*)d_in[0];  // (16, 9, 128, 128)
    const float* V   = (const float*)d_in[1];  // (16, 64, 128, 128)
    float* out       = (float*)d_out;          // (16, 64, 128, 128)

    msa_conv2d_kernel<<<dim3(2048), 256, 0, stream>>>(Dot, V, out);
}